// Round 10
// baseline (19.136 us; speedup 1.0000x reference)
//
#include <hip/hip_runtime.h>

// Shapes (compile-time constants from the reference)
#define BQ 4     // B
#define VV 384   // V visible nodes
#define HH 128   // H hidden nodes
#define NN 512   // N = V + H
#define HDIM 64  // HD
#define TD 128   // T*D

// Wave-uniform broadcast: readlane (VALU->SGPR, ~4cyc) instead of __shfl
// (ds_bpermute, ~60+cyc LDS-crossbar latency). Index must be wave-uniform.
__device__ __forceinline__ float BCAST(float v, int l) {
    return __int_as_float(__builtin_amdgcn_readlane(__float_as_int(v), l));
}

// K1: visible rows only; ONE wave per row, zero barriers, zero LDS.
// Chain: x(coalesced) -> in1 -> in2 -> e1(sender) -> e2 -> E2 row.
// 64-thread blocks: 1536 blocks = exactly 6 waves/CU, no imbalance.
__global__ __launch_bounds__(64) void k_rowpipe(
    const float* __restrict__ x,       // (B*V,128)
    const float* __restrict__ w_in1,   // (128,64)
    const float* __restrict__ b_in1,   // (64)
    const float* __restrict__ w_in2,   // (64,64)
    const float* __restrict__ b_in2,   // (64)
    const float* __restrict__ w_e1,    // (128,64) ; rows [64:128) = sender half
    const float* __restrict__ b_e1,    // (64)
    const float* __restrict__ w_e2,    // (64,64)
    const float* __restrict__ b_e2,    // (64)
    float* __restrict__ E2)            // (B*V,64) in workspace
{
    const int row  = blockIdx.x;          // 0 .. B*V-1
    const int lane = threadIdx.x;         // 0..63

    const float* xr = x + (size_t)row * TD;
    const float xv0 = xr[lane];
    const float xv1 = xr[64 + lane];

    // layer in1: K=128
    float a0 = b_in1[lane], a1 = 0.f;
    #pragma unroll 8
    for (int k = 0; k < HDIM; ++k) {
        a0 = fmaf(BCAST(xv0, k), w_in1[k * HDIM + lane],          a0);
        a1 = fmaf(BCAST(xv1, k), w_in1[(HDIM + k) * HDIM + lane], a1);
    }
    const float h1 = fmaxf(a0 + a1, 0.f);

    // layer in2: K=64
    a0 = b_in2[lane]; a1 = 0.f;
    #pragma unroll 8
    for (int k = 0; k < HDIM; k += 2) {
        a0 = fmaf(BCAST(h1, k),     w_in2[k * HDIM + lane],       a0);
        a1 = fmaf(BCAST(h1, k + 1), w_in2[(k + 1) * HDIM + lane], a1);
    }
    const float h2 = fmaxf(a0 + a1, 0.f);

    // sender-side edge contribution: bb = h2 @ w_e1[HD:]
    a0 = 0.f; a1 = 0.f;
    #pragma unroll 8
    for (int k = 0; k < HDIM; k += 2) {
        a0 = fmaf(BCAST(h2, k),     w_e1[(HDIM + k) * HDIM + lane],     a0);
        a1 = fmaf(BCAST(h2, k + 1), w_e1[(HDIM + k + 1) * HDIM + lane], a1);
    }
    const float e1 = fmaxf(a0 + a1 + b_e1[lane], 0.f);

    // edge layer 2
    a0 = b_e2[lane]; a1 = 0.f;
    #pragma unroll 8
    for (int k = 0; k < HDIM; k += 2) {
        a0 = fmaf(BCAST(e1, k),     w_e2[k * HDIM + lane],       a0);
        a1 = fmaf(BCAST(e1, k + 1), w_e2[(k + 1) * HDIM + lane], a1);
    }
    E2[(size_t)row * HDIM + lane] = fmaxf(a0 + a1, 0.f);
}

// K2: 256 blocks x 1024 threads (16 waves), 2 hidden rows per block.
// Phase A (all waves): 12 visible-agg waves + 4 hidden-sum waves -> redA/hs/e2c.
// ONE barrier. Phase B: waves w8 in {0,1} of each row-group run the whole
// tail redundantly in registers (no further barriers); 12 waves exit.
__global__ __launch_bounds__(1024) void k_agg_out(
    const float* __restrict__ adj,   // (B,N,N)
    const float* __restrict__ E2,    // (B*V,64)
    const float* __restrict__ b_e1, const float* __restrict__ w_e2,
    const float* __restrict__ b_e2,
    const float* __restrict__ w_n1, const float* __restrict__ b_n1,
    const float* __restrict__ w_n2, const float* __restrict__ b_n2,
    const float* __restrict__ w_out, // (64,128)
    const float* __restrict__ b_out, // (128)
    float* __restrict__ out)         // (B,H,128)
{
    const int blk  = blockIdx.x;          // 0..255
    const int b    = blk >> 6;
    const int pair = blk & 63;
    const int wid  = threadIdx.x >> 6;    // 0..15
    const int lane = threadIdx.x & 63;

    const int i0 = VV + pair * 2;
    const float* adjr0 = adj + ((size_t)b * NN + i0) * NN;
    const float* adjr1 = adjr0 + NN;
    const int j0 = wid * 32;              // waves 0-11 visible, 12-15 hidden

    // 32 senders for both rows in one coalesced load
    const float adjv = (lane < 32) ? adjr0[j0 + lane] : adjr1[j0 + lane - 32];

    __shared__ float redA[12][2][HDIM];
    __shared__ float hs[4][2];
    __shared__ float e2c[HDIM];

    if (wid < 12) {
        const float* e2b = E2 + ((size_t)b * VV + j0) * HDIM;
        float p0 = 0.f, p1 = 0.f, q0 = 0.f, q1 = 0.f;
        #pragma unroll 8
        for (int jj = 0; jj < 32; jj += 2) {
            const float e0 = e2b[jj * HDIM + lane];
            const float e1 = e2b[(jj + 1) * HDIM + lane];
            p0 = fmaf(BCAST(adjv, jj),      e0, p0);
            q0 = fmaf(BCAST(adjv, 32 + jj), e0, q0);
            p1 = fmaf(BCAST(adjv, jj + 1),  e1, p1);
            q1 = fmaf(BCAST(adjv, 33 + jj), e1, q1);
        }
        redA[wid][0][lane] = p0 + p1;
        redA[wid][1][lane] = q0 + q1;
    } else {
        // hidden senders: row-sum of adj chunk per row via 32-lane tree
        float s = adjv;
        s += __shfl_xor(s, 1, 64);
        s += __shfl_xor(s, 2, 64);
        s += __shfl_xor(s, 4, 64);
        s += __shfl_xor(s, 8, 64);
        s += __shfl_xor(s, 16, 64);
        if (lane == 0)  hs[wid - 12][0] = s;
        if (lane == 32) hs[wid - 12][1] = s;
        if (wid == 12) {
            // constant hidden-sender E2 vector: relu(relu(b_e1)@w_e2 + b_e2)
            const float e1c = fmaxf(b_e1[lane], 0.f);
            float t0 = b_e2[lane], t1 = 0.f;
            #pragma unroll 8
            for (int k = 0; k < HDIM; k += 2) {
                t0 = fmaf(BCAST(e1c, k),     w_e2[k * HDIM + lane],       t0);
                t1 = fmaf(BCAST(e1c, k + 1), w_e2[(k + 1) * HDIM + lane], t1);
            }
            e2c[lane] = fmaxf(t0 + t1, 0.f);
        }
    }
    __syncthreads();

    const int g  = wid >> 3;   // row group (0/1)
    const int w8 = wid & 7;
    if (w8 >= 2) return;       // 12 waves done; 4 waves run the tail

    // agg for row g
    const float hsum = hs[0][g] + hs[1][g] + hs[2][g] + hs[3][g];
    float agg = hsum * e2c[lane];
    #pragma unroll
    for (int w = 0; w < 12; ++w) agg += redA[w][g][lane];

    // node MLP, fully in-registers (redundant across the 2 tail waves)
    float t0 = b_n1[lane], t1 = 0.f;
    #pragma unroll 8
    for (int k = 0; k < HDIM; k += 2) {
        t0 = fmaf(BCAST(agg, k),     w_n1[k * HDIM + lane],       t0);
        t1 = fmaf(BCAST(agg, k + 1), w_n1[(k + 1) * HDIM + lane], t1);
    }
    const float n1 = fmaxf(t0 + t1, 0.f);

    t0 = b_n2[lane]; t1 = 0.f;
    #pragma unroll 8
    for (int k = 0; k < HDIM; k += 2) {
        t0 = fmaf(BCAST(n1, k),     w_n2[k * HDIM + lane],       t0);
        t1 = fmaf(BCAST(n1, k + 1), w_n2[(k + 1) * HDIM + lane], t1);
    }
    const float n2 = fmaxf(t0 + t1, 0.f);

    // out layer: wave w8 covers cols [64*w8, 64*w8+64)
    const int col = 64 * w8 + lane;
    float o0 = b_out[col], o1 = 0.f;
    #pragma unroll 8
    for (int k = 0; k < HDIM; k += 2) {
        o0 = fmaf(BCAST(n2, k),     w_out[k * TD + col],       o0);
        o1 = fmaf(BCAST(n2, k + 1), w_out[(k + 1) * TD + col], o1);
    }
    const int orow = b * HH + pair * 2 + g;
    out[(size_t)orow * TD + col] = o0 + o1;
}

extern "C" void kernel_launch(void* const* d_in, const int* in_sizes, int n_in,
                              void* d_out, int out_size, void* d_ws, size_t ws_size,
                              hipStream_t stream) {
    const float* x     = (const float*)d_in[0];
    const float* adj   = (const float*)d_in[1];
    const float* w_in1 = (const float*)d_in[2];
    const float* b_in1 = (const float*)d_in[3];
    const float* w_in2 = (const float*)d_in[4];
    const float* b_in2 = (const float*)d_in[5];
    const float* w_e1  = (const float*)d_in[6];
    const float* b_e1  = (const float*)d_in[7];
    const float* w_e2  = (const float*)d_in[8];
    const float* b_e2  = (const float*)d_in[9];
    const float* w_n1  = (const float*)d_in[10];
    const float* b_n1  = (const float*)d_in[11];
    const float* w_n2  = (const float*)d_in[12];
    const float* b_n2  = (const float*)d_in[13];
    const float* w_out = (const float*)d_in[14];
    const float* b_out = (const float*)d_in[15];
    float* out = (float*)d_out;
    float* E2  = (float*)d_ws;   // B*V*64 floats = 384 KiB

    // K1: one 64-thread block per visible row -> 1536 blocks (6 waves/CU)
    k_rowpipe<<<BQ * VV, 64, 0, stream>>>(
        x, w_in1, b_in1, w_in2, b_in2, w_e1, b_e1, w_e2, b_e2, E2);
    // K2: 256 blocks x 1024 threads, 2 hidden rows per block
    k_agg_out<<<BQ * HH / 2, 1024, 0, stream>>>(
        adj, E2, b_e1, w_e2, b_e2, w_n1, b_n1, w_n2, b_n2, w_out, b_out, out);
}